// Round 2
// baseline (98.908 us; speedup 1.0000x reference)
//
#include <hip/hip_runtime.h>
#include <cstdint>

// Lukasiewicz max-plus matmul: y[n,o] = max(b[o], max(0, max_i(x[n,i]+a[o,i]-1)))
// N=2048, K=512, OUT=512, fp32. VALU-bound (no max-plus MFMA).
//
// R2: 2-way K-split -> 512 blocks = 2 blocks/CU = 2 waves/SIMD (was 1; kernel
// was latency-bound at 9.3% occupancy). Partials combined via int atomicMax
// (all values >= 0 after clamp, so int order == float order; max is assoc ->
// deterministic). Inner step: f32x4 add (v_pk_add_f32) + 2 max3-shaped chains.

#define TILE 64
#define BK   64
#define NROW 2048
#define NK   512
#define NCOL 512
#define KSPLIT 2
#define NKT  (NK / BK / KSPLIT)   // 4 k-tiles per block

typedef float f32x4 __attribute__((ext_vector_type(4)));

__device__ __forceinline__ void async_load16(const float* g, float* l) {
  __builtin_amdgcn_global_load_lds(
      (const __attribute__((address_space(1))) void*)g,
      (__attribute__((address_space(3))) void*)l,
      16, 0, 0);
}

__global__ __launch_bounds__(256) void luka_kernel(
    const float* __restrict__ X, const float* __restrict__ A,
    const float* __restrict__ Bv, float* __restrict__ Y) {
  __shared__ float xs[2][TILE * BK];   // 2 x 16KB
  __shared__ float as[2][TILE * BK];   // 2 x 16KB  -> 64KB total
  const int tid  = threadIdx.x;
  const int wave = tid >> 6;
  const int tx   = tid & 15;
  const int ty   = tid >> 4;
  const int rowBase = blockIdx.y * TILE;
  const int colBase = blockIdx.x * TILE;
  const int ktBase  = blockIdx.z * NKT;

  // Swizzle m(row) = (row&15)^(row>>2): x-reads 4 distinct slots, a-reads 16
  // distinct slots -> 0 bank conflicts (verified R1: SQ_LDS_BANK_CONFLICT=0).
  uint32_t xoff[4], aoff[4];
#pragma unroll
  for (int r = 0; r < 4; ++r) {
    int row = ty * 4 + r;
    xoff[r] = (uint32_t)row * 256u + ((uint32_t)((row & 15) ^ (row >> 2)) << 4);
  }
#pragma unroll
  for (int c = 0; c < 4; ++c) {
    int row = tx * 4 + c;
    aoff[c] = (uint32_t)row * 256u + ((uint32_t)((row & 15) ^ (row >> 2)) << 4);
  }

  float acc[4][4];
#pragma unroll
  for (int r = 0; r < 4; ++r)
#pragma unroll
    for (int c = 0; c < 4; ++c) acc[r][c] = 0.0f;

  const int row0 = tid >> 4;
  const int sl   = tid & 15;

  // Linear LDS dest + inverse-swizzled GLOBAL source (rule #21).
  auto stage = [&](int buf, int kt) {
#pragma unroll
    for (int j = 0; j < 4; ++j) {
      int row = row0 + j * 16;
      int m   = (row & 15) ^ (row >> 2);
      int kk  = ((sl ^ m) << 2);
      const float* gx = X + (size_t)(rowBase + row) * NK + kt * BK + kk;
      const float* ga = A + (size_t)(colBase + row) * NK + kt * BK + kk;
      async_load16(gx, &xs[buf][j * 1024 + wave * 256]);
      async_load16(ga, &as[buf][j * 1024 + wave * 256]);
    }
  };

  stage(0, ktBase);
  __syncthreads();

  int buf = 0;
#pragma unroll 1
  for (int t = 0; t < NKT; ++t) {
    if (t < NKT - 1) stage(buf ^ 1, ktBase + t + 1);

    const char* xb = (const char*)&xs[buf][0];
    const char* ab = (const char*)&as[buf][0];
#pragma unroll
    for (int s4 = 0; s4 < BK / 4; ++s4) {
      f32x4 xf[4], af[4];
#pragma unroll
      for (int r = 0; r < 4; ++r)
        xf[r] = *(const f32x4*)(xb + (xoff[r] ^ (uint32_t)(s4 << 4)));
#pragma unroll
      for (int c = 0; c < 4; ++c)
        af[c] = *(const f32x4*)(ab + (aoff[c] ^ (uint32_t)(s4 << 4)));
#pragma unroll
      for (int r = 0; r < 4; ++r) {
#pragma unroll
        for (int c = 0; c < 4; ++c) {
          f32x4 s = xf[r] + af[c];                      // 2x v_pk_add_f32
          float t0 = fmaxf(fmaxf(s.x, s.y), acc[r][c]); // v_max3
          acc[r][c] = fmaxf(fmaxf(s.z, s.w), t0);       // v_max3
        }
      }
    }
    __syncthreads();
    buf ^= 1;
  }

  // Per-block value = max(acc-1, 0, b) >= 0; combine across K-halves with int
  // atomicMax (non-negative IEEE floats are int-ordered). Y is memset to 0.
  const f32x4 bv = *(const f32x4*)&Bv[colBase + tx * 4];
  float bvv[4] = {bv.x, bv.y, bv.z, bv.w};
  int* Yi = (int*)Y;
#pragma unroll
  for (int r = 0; r < 4; ++r) {
    int base = (rowBase + ty * 4 + r) * NCOL + colBase + tx * 4;
#pragma unroll
    for (int c = 0; c < 4; ++c) {
      float t = fmaxf(fmaxf(acc[r][c] - 1.0f, bvv[c]), 0.0f);
      atomicMax(&Yi[base + c], __float_as_int(t));
    }
  }
}

extern "C" void kernel_launch(void* const* d_in, const int* in_sizes, int n_in,
                              void* d_out, int out_size, void* d_ws, size_t ws_size,
                              hipStream_t stream) {
  const float* X = (const float*)d_in[0];   // [2048][512]
  const float* A = (const float*)d_in[1];   // [512][512]
  const float* B = (const float*)d_in[2];   // [512]
  float* Y = (float*)d_out;                 // [2048][512]
  hipMemsetAsync(Y, 0, (size_t)out_size * sizeof(float), stream);
  dim3 grid(NCOL / TILE, NROW / TILE, KSPLIT);  // (8, 32, 2) = 512 blocks
  luka_kernel<<<grid, dim3(256), 0, stream>>>(X, A, B, Y);
}